// Round 4
// baseline (1259.838 us; speedup 1.0000x reference)
//
#include <hip/hip_runtime.h>
#include <cstddef>

#define NSAMP 16
#define HW 409600
#define CPRED 6
#define EPS 1e-6

#define NB1 2048      // top-11 bits
#define NB2 2048      // next-11 bits
#define NB3 1024      // low-10 bits
#define L1SHIFT 21
#define BPSH 50       // blocks/sample, histogram passes (50*256*32 = 409600)
#define BPSD 100      // blocks/sample, dice pass
#define BPSC 25       // blocks/sample, compact refine passes

__device__ __forceinline__ unsigned sortkey(float f) {
    unsigned b = __float_as_uint(f);
    return (b & 0x80000000u) ? ~b : (b | 0x80000000u);   // larger float -> larger key
}
__device__ __forceinline__ float inv_sortkey(unsigned k) {
    unsigned b = (k & 0x80000000u) ? (k ^ 0x80000000u) : ~k;
    return __uint_as_float(b);
}
__device__ __forceinline__ float sigmoidf(float x) {
    return 1.0f / (1.0f + __expf(-x));
}

// Pass 1: pos/neg counts + level-1 LDS histogram + (optional) compact negative keys.
__global__ void k_stats(const float* __restrict__ preds,
                        const float* __restrict__ targets,
                        const float* __restrict__ eff,
                        unsigned* __restrict__ hist,
                        unsigned* __restrict__ pos,
                        unsigned* __restrict__ negc,
                        unsigned* __restrict__ nkeys,   // may be null
                        unsigned* __restrict__ keys) {  // may be null
    const int n = blockIdx.y;
    const float4* p4 = (const float4*)(preds + (size_t)n * CPRED * HW);
    const float4* t4 = (const float4*)(targets + (size_t)n * 2 * HW);
    const float4* e4 = (const float4*)(eff + (size_t)n * HW);
    __shared__ unsigned h[4][NB1];
    for (int i = threadIdx.x; i < 4 * NB1; i += 256) ((unsigned*)h)[i] = 0;
    __syncthreads();
    const int wave = threadIdx.x >> 6;
    const int lane = threadIdx.x & 63;
    unsigned* kout = keys ? keys + (size_t)n * HW : nullptr;
    unsigned lp = 0, ln = 0;
    const int base = blockIdx.x * 2048;   // float4 units; 8192 floats/block
#pragma unroll
    for (int k = 0; k < 8; k++) {
        int i = base + k * 256 + threadIdx.x;
        float4 p = p4[i], t = t4[i], e = e4[i];
        float pa[4] = {p.x, p.y, p.z, p.w};
        float ta[4] = {t.x, t.y, t.z, t.w};
        float ea[4] = {e.x, e.y, e.z, e.w};
#pragma unroll
        for (int j = 0; j < 4; j++) {
            lp += (ta[j] > 0.5f && ea[j] > 0.5f) ? 1u : 0u;
            const bool isneg = (ta[j] <= 0.5f);
            unsigned key = sortkey(pa[j]);
            if (isneg) {
                ln++;
                atomicAdd(&h[wave][key >> L1SHIFT], 1u);
            }
            if (kout) {
                unsigned long long bm = __ballot(isneg);
                int cnt = __popcll(bm);
                if (cnt) {
                    int rank = __popcll(bm & ((1ull << lane) - 1ull));
                    unsigned basep = 0;
                    if (lane == 0) basep = atomicAdd(&nkeys[n], (unsigned)cnt);
                    basep = __shfl(basep, 0, 64);
                    if (isneg) kout[basep + rank] = key;
                }
            }
        }
    }
    for (int off = 32; off; off >>= 1) {
        lp += __shfl_down(lp, off, 64);
        ln += __shfl_down(ln, off, 64);
    }
    if (lane == 0) {
        atomicAdd(&pos[n], lp);
        atomicAdd(&negc[n], ln);
    }
    __syncthreads();
    unsigned* gh = hist + (size_t)n * NB1;
    for (int b = threadIdx.x; b < NB1; b += 256) {
        unsigned s = h[0][b] + h[1][b] + h[2][b] + h[3][b];
        if (s) atomicAdd(&gh[b], s);
    }
}

__global__ void k_scan1(unsigned* __restrict__ hist,
                        const unsigned* __restrict__ pos,
                        const unsigned* __restrict__ negc,
                        unsigned* __restrict__ b1,
                        unsigned* __restrict__ rem1,
                        unsigned* __restrict__ fb) {
    const int n = blockIdx.x;
    unsigned* gh = hist + (size_t)n * NB1;
    __shared__ unsigned bins[NB1];
    __shared__ unsigned chunkSum[256];
    for (int i = threadIdx.x; i < NB1; i += 256) bins[i] = gh[i];
    __syncthreads();
    for (int i = threadIdx.x; i < NB1; i += 256) gh[i] = 0;   // reuse for level 2
    unsigned s = 0;
#pragma unroll
    for (int j = 0; j < 8; j++) s += bins[threadIdx.x * 8 + j];
    chunkSum[threadIdx.x] = s;
    __syncthreads();
    if (threadIdx.x == 0) {
        const unsigned p = pos[n], nc = negc[n];
        const unsigned nn = min(p * 3u, nc);
        if (p == 0 || nn == 0) {
            b1[n] = 0xFFFFFFFFu; rem1[n] = 0; fb[n] = 1u;
        } else {
            fb[n] = 0u;
            unsigned cum = 0;
            int c;
            for (c = 255;; c--) {
                if (cum + chunkSum[c] >= nn) break;
                cum += chunkSum[c];
            }
            int b;
            for (b = c * 8 + 7;; b--) {
                unsigned hv = bins[b];
                if (cum + hv >= nn) break;
                cum += hv;
            }
            b1[n] = (unsigned)b;
            rem1[n] = nn - cum;
        }
    }
}

// Compact-path level-2: histogram next-11 bits of stored keys matching b1.
__global__ void k_refine2_c(const unsigned* __restrict__ keys,
                            const unsigned* __restrict__ nkeys,
                            const unsigned* __restrict__ b1,
                            unsigned* __restrict__ hist) {
    const int n = blockIdx.y;
    const unsigned B1 = b1[n];
    if (B1 == 0xFFFFFFFFu) return;
    const unsigned nk = nkeys[n];
    const unsigned* kin = keys + (size_t)n * HW;
    __shared__ unsigned h[4][NB2];
    for (int i = threadIdx.x; i < 4 * NB2; i += 256) ((unsigned*)h)[i] = 0;
    __syncthreads();
    const int wave = threadIdx.x >> 6;
    for (unsigned i = blockIdx.x * 256 + threadIdx.x; i < nk; i += BPSC * 256) {
        unsigned key = kin[i];
        if ((key >> L1SHIFT) == B1)
            atomicAdd(&h[wave][(key >> 10) & 0x7FFu], 1u);
    }
    __syncthreads();
    unsigned* gh = hist + (size_t)n * NB1;
    for (int b = threadIdx.x; b < NB2; b += 256) {
        unsigned s = h[0][b] + h[1][b] + h[2][b] + h[3][b];
        if (s) atomicAdd(&gh[b], s);
    }
}

// Fallback level-2 (re-reads pred/target) when ws too small for keys.
__global__ void k_refine2_g(const float* __restrict__ preds,
                            const float* __restrict__ targets,
                            const unsigned* __restrict__ b1,
                            unsigned* __restrict__ hist) {
    const int n = blockIdx.y;
    const unsigned B1 = b1[n];
    if (B1 == 0xFFFFFFFFu) return;
    const float4* p4 = (const float4*)(preds + (size_t)n * CPRED * HW);
    const float4* t4 = (const float4*)(targets + (size_t)n * 2 * HW);
    __shared__ unsigned h[4][NB2];
    for (int i = threadIdx.x; i < 4 * NB2; i += 256) ((unsigned*)h)[i] = 0;
    __syncthreads();
    const int wave = threadIdx.x >> 6;
    const int base = blockIdx.x * 2048;
#pragma unroll
    for (int k = 0; k < 8; k++) {
        int i = base + k * 256 + threadIdx.x;
        float4 p = p4[i], t = t4[i];
        float pa[4] = {p.x, p.y, p.z, p.w};
        float ta[4] = {t.x, t.y, t.z, t.w};
#pragma unroll
        for (int j = 0; j < 4; j++) {
            if (ta[j] <= 0.5f) {
                unsigned key = sortkey(pa[j]);
                if ((key >> L1SHIFT) == B1)
                    atomicAdd(&h[wave][(key >> 10) & 0x7FFu], 1u);
            }
        }
    }
    __syncthreads();
    unsigned* gh = hist + (size_t)n * NB1;
    for (int b = threadIdx.x; b < NB2; b += 256) {
        unsigned s = h[0][b] + h[1][b] + h[2][b] + h[3][b];
        if (s) atomicAdd(&gh[b], s);
    }
}

__global__ void k_scan2(unsigned* __restrict__ hist,
                        const unsigned* __restrict__ fb,
                        const unsigned* __restrict__ rem1,
                        unsigned* __restrict__ b2,
                        unsigned* __restrict__ rem2) {
    const int n = blockIdx.x;
    unsigned* gh = hist + (size_t)n * NB1;
    __shared__ unsigned bins[NB2];
    __shared__ unsigned chunkSum[256];
    for (int i = threadIdx.x; i < NB2; i += 256) bins[i] = gh[i];
    __syncthreads();
    for (int i = threadIdx.x; i < NB2; i += 256) gh[i] = 0;   // reuse for level 3
    unsigned s = 0;
#pragma unroll
    for (int j = 0; j < 8; j++) s += bins[threadIdx.x * 8 + j];
    chunkSum[threadIdx.x] = s;
    __syncthreads();
    if (threadIdx.x == 0) {
        if (fb[n]) { b2[n] = 0; rem2[n] = 0; return; }
        const unsigned r = rem1[n];
        unsigned cum = 0;
        int c;
        for (c = 255;; c--) {
            if (cum + chunkSum[c] >= r) break;
            cum += chunkSum[c];
        }
        int b;
        for (b = c * 8 + 7;; b--) {
            unsigned hv = bins[b];
            if (cum + hv >= r) break;
            cum += hv;
        }
        b2[n] = (unsigned)b;
        rem2[n] = r - cum;
    }
}

// Compact-path level-3.
__global__ void k_refine3_c(const unsigned* __restrict__ keys,
                            const unsigned* __restrict__ nkeys,
                            const unsigned* __restrict__ b1,
                            const unsigned* __restrict__ b2,
                            unsigned* __restrict__ hist) {
    const int n = blockIdx.y;
    const unsigned B1 = b1[n];
    if (B1 == 0xFFFFFFFFu) return;
    const unsigned prefix = (B1 << 11) | b2[n];
    const unsigned nk = nkeys[n];
    const unsigned* kin = keys + (size_t)n * HW;
    __shared__ unsigned h[4][NB3];
    for (int i = threadIdx.x; i < 4 * NB3; i += 256) ((unsigned*)h)[i] = 0;
    __syncthreads();
    const int wave = threadIdx.x >> 6;
    for (unsigned i = blockIdx.x * 256 + threadIdx.x; i < nk; i += BPSC * 256) {
        unsigned key = kin[i];
        if ((key >> 10) == prefix)
            atomicAdd(&h[wave][key & 0x3FFu], 1u);
    }
    __syncthreads();
    unsigned* gh = hist + (size_t)n * NB1;
    for (int b = threadIdx.x; b < NB3; b += 256) {
        unsigned s = h[0][b] + h[1][b] + h[2][b] + h[3][b];
        if (s) atomicAdd(&gh[b], s);
    }
}

// Fallback level-3.
__global__ void k_refine3_g(const float* __restrict__ preds,
                            const float* __restrict__ targets,
                            const unsigned* __restrict__ b1,
                            const unsigned* __restrict__ b2,
                            unsigned* __restrict__ hist) {
    const int n = blockIdx.y;
    const unsigned B1 = b1[n];
    if (B1 == 0xFFFFFFFFu) return;
    const unsigned prefix = (B1 << 11) | b2[n];
    const float4* p4 = (const float4*)(preds + (size_t)n * CPRED * HW);
    const float4* t4 = (const float4*)(targets + (size_t)n * 2 * HW);
    __shared__ unsigned h[4][NB3];
    for (int i = threadIdx.x; i < 4 * NB3; i += 256) ((unsigned*)h)[i] = 0;
    __syncthreads();
    const int wave = threadIdx.x >> 6;
    const int base = blockIdx.x * 2048;
#pragma unroll
    for (int k = 0; k < 8; k++) {
        int i = base + k * 256 + threadIdx.x;
        float4 p = p4[i], t = t4[i];
        float pa[4] = {p.x, p.y, p.z, p.w};
        float ta[4] = {t.x, t.y, t.z, t.w};
#pragma unroll
        for (int j = 0; j < 4; j++) {
            if (ta[j] <= 0.5f) {
                unsigned key = sortkey(pa[j]);
                if ((key >> 10) == prefix)
                    atomicAdd(&h[wave][key & 0x3FFu], 1u);
            }
        }
    }
    __syncthreads();
    unsigned* gh = hist + (size_t)n * NB1;
    for (int b = threadIdx.x; b < NB3; b += 256) {
        unsigned s = h[0][b] + h[1][b] + h[2][b] + h[3][b];
        if (s) atomicAdd(&gh[b], s);
    }
}

__global__ void k_scan3(const unsigned* __restrict__ hist,
                        const unsigned* __restrict__ fb,
                        const unsigned* __restrict__ b1,
                        const unsigned* __restrict__ b2,
                        const unsigned* __restrict__ rem2,
                        float* __restrict__ thr) {
    const int n = blockIdx.x;
    const unsigned* gh = hist + (size_t)n * NB1;
    __shared__ unsigned bins[NB3];
    __shared__ unsigned chunkSum[256];
    for (int i = threadIdx.x; i < NB3; i += 256) bins[i] = gh[i];
    __syncthreads();
    unsigned s = 0;
#pragma unroll
    for (int j = 0; j < 4; j++) s += bins[threadIdx.x * 4 + j];
    chunkSum[threadIdx.x] = s;
    __syncthreads();
    if (threadIdx.x == 0) {
        if (fb[n]) { thr[n] = -INFINITY; return; }
        const unsigned r = rem2[n];
        unsigned cum = 0;
        int c;
        for (c = 255;; c--) {
            if (cum + chunkSum[c] >= r) break;
            cum += chunkSum[c];
        }
        int b;
        for (b = c * 4 + 3;; b--) {
            unsigned hv = bins[b];
            if (cum + hv >= r) break;
            cum += hv;
        }
        thr[n] = inv_sortkey((b1[n] << L1SHIFT) | (b2[n] << 10) | (unsigned)b);
    }
}

// Pass 5: fused sigmoid + masks + 6 dice partial sums per block (no atomics).
__global__ void k_dice(const float* __restrict__ preds,
                       const float* __restrict__ targets,
                       const float* __restrict__ eff,
                       const float* __restrict__ thr,
                       const unsigned* __restrict__ fb,
                       double* __restrict__ partials) {
    const int n = blockIdx.y;
    const float4* p0 = (const float4*)(preds + (size_t)n * CPRED * HW);
    const float4* p1 = (const float4*)(preds + (size_t)n * CPRED * HW + HW);
    const float4* t0 = (const float4*)(targets + (size_t)n * 2 * HW);
    const float4* t1 = (const float4*)(targets + (size_t)n * 2 * HW + HW);
    const float4* e4 = (const float4*)(eff + (size_t)n * HW);
    const float th = thr[n];
    const bool fallback = fb[n] != 0;
    float sPG = 0.f, sP2 = 0.f, sG2 = 0.f, sPGk = 0.f, sP2k = 0.f, sG2k = 0.f;
    const int base = blockIdx.x * 1024;
#pragma unroll
    for (int k = 0; k < 4; k++) {
        int i = base + k * 256 + threadIdx.x;
        float4 a = p0[i], b = p1[i], t = t0[i], u = t1[i], e = e4[i];
        float pa[4] = {a.x, a.y, a.z, a.w};
        float pb[4] = {b.x, b.y, b.z, b.w};
        float ta[4] = {t.x, t.y, t.z, t.w};
        float ua[4] = {u.x, u.y, u.z, u.w};
        float ea[4] = {e.x, e.y, e.z, e.w};
#pragma unroll
        for (int j = 0; j < 4; j++) {
            float pt = sigmoidf(pa[j]);
            float pk = sigmoidf(pb[j]);
            float tbt = (ta[j] > 0.5f) ? 1.f : 0.f;
            float tbk = (ua[j] > 0.5f) ? 1.f : 0.f;
            float m;
            if (fallback) m = ea[j];
            else m = (((pa[j] >= th) || (ta[j] > 0.5f)) && (ea[j] > 0.5f)) ? 1.f : 0.f;
            float Pm = pt * m, Tm = tbt * m;
            sPG += Pm * Tm; sP2 += Pm * Pm; sG2 += Tm * Tm;
            float mk = (pt > 0.5f && ea[j] > 0.5f) ? 1.f : 0.f;
            float Pk = pk * mk, Tk = tbk * mk;
            sPGk += Pk * Tk; sP2k += Pk * Pk; sG2k += Tk * Tk;
        }
    }
    for (int off = 32; off; off >>= 1) {
        sPG  += __shfl_down(sPG, off, 64);
        sP2  += __shfl_down(sP2, off, 64);
        sG2  += __shfl_down(sG2, off, 64);
        sPGk += __shfl_down(sPGk, off, 64);
        sP2k += __shfl_down(sP2k, off, 64);
        sG2k += __shfl_down(sG2k, off, 64);
    }
    __shared__ double ws[4][6];
    if ((threadIdx.x & 63) == 0) {
        const int w = threadIdx.x >> 6;
        ws[w][0] = sPG;  ws[w][1] = sP2;  ws[w][2] = sG2;
        ws[w][3] = sPGk; ws[w][4] = sP2k; ws[w][5] = sG2k;
    }
    __syncthreads();
    if (threadIdx.x < 6) {
        double v = ws[0][threadIdx.x] + ws[1][threadIdx.x] +
                   ws[2][threadIdx.x] + ws[3][threadIdx.x];
        partials[((size_t)n * BPSD + blockIdx.x) * 6 + threadIdx.x] = v;
    }
}

// Pass 6: reduce partials, emit 32 outputs.
__global__ void k_final(const double* __restrict__ partials, float* __restrict__ out) {
    __shared__ double ssum[96];
    const int t = threadIdx.x;
    if (t < 96) {
        const int n = t / 6, c = t % 6;
        double a = 0.0;
        for (int b = 0; b < BPSD; b++) a += partials[((size_t)n * BPSD + b) * 6 + c];
        ssum[t] = a;
    }
    __syncthreads();
    if (t < NSAMP) {
        const double* s = &ssum[t * 6];
        out[t]         = (float)(1.0 - 2.0 * s[0] / (s[1] + s[2] + EPS));
        out[NSAMP + t] = (float)(1.0 - 2.0 * s[3] / (s[4] + s[5] + EPS));
    }
}

extern "C" void kernel_launch(void* const* d_in, const int* in_sizes, int n_in,
                              void* d_out, int out_size, void* d_ws, size_t ws_size,
                              hipStream_t stream) {
    const float* preds = (const float*)d_in[0];
    const float* targets = (const float*)d_in[1];
    const float* eff = (const float*)d_in[2];
    float* out = (float*)d_out;

    char* ws = (char*)d_ws;
    const size_t HIST_BYTES = (size_t)NSAMP * NB1 * sizeof(unsigned);   // 128 KiB
    unsigned* hist = (unsigned*)ws;
    unsigned* pos  = (unsigned*)(ws + HIST_BYTES);
    unsigned* negc = pos + NSAMP;
    unsigned* b1   = negc + NSAMP;
    unsigned* b2   = b1 + NSAMP;
    unsigned* rem1 = b2 + NSAMP;
    unsigned* rem2 = rem1 + NSAMP;
    unsigned* fb   = rem2 + NSAMP;
    float*    thr  = (float*)(fb + NSAMP);
    unsigned* nkeys = (unsigned*)(ws + HIST_BYTES + 512);               // 64 B
    double*   partials = (double*)(ws + HIST_BYTES + 1024);             // 16*100*6*8 = 76800 B
    const size_t KEYS_OFF = HIST_BYTES + 1024 + 80000;                  // 8-aligned
    unsigned* keys = (unsigned*)(ws + KEYS_OFF);
    const size_t KEYS_BYTES = (size_t)NSAMP * HW * sizeof(unsigned);    // 26.2 MB
    const bool compact = (ws_size >= KEYS_OFF + KEYS_BYTES);

    // zero hist + small arrays + nkeys (partials fully overwritten; keys count-guarded)
    hipMemsetAsync(d_ws, 0, HIST_BYTES + 1024, stream);

    dim3 bh(BPSH, NSAMP);
    dim3 bc(BPSC, NSAMP);
    dim3 bd(BPSD, NSAMP);
    k_stats<<<bh, 256, 0, stream>>>(preds, targets, eff, hist, pos, negc,
                                    compact ? nkeys : nullptr,
                                    compact ? keys : nullptr);
    k_scan1<<<NSAMP, 256, 0, stream>>>(hist, pos, negc, b1, rem1, fb);
    if (compact) k_refine2_c<<<bc, 256, 0, stream>>>(keys, nkeys, b1, hist);
    else         k_refine2_g<<<bh, 256, 0, stream>>>(preds, targets, b1, hist);
    k_scan2<<<NSAMP, 256, 0, stream>>>(hist, fb, rem1, b2, rem2);
    if (compact) k_refine3_c<<<bc, 256, 0, stream>>>(keys, nkeys, b1, b2, hist);
    else         k_refine3_g<<<bh, 256, 0, stream>>>(preds, targets, b1, b2, hist);
    k_scan3<<<NSAMP, 256, 0, stream>>>(hist, fb, b1, b2, rem2, thr);
    k_dice <<<bd, 256, 0, stream>>>(preds, targets, eff, thr, fb, partials);
    k_final<<<1, 128, 0, stream>>>(partials, out);
}

// Round 5
// 142.758 us; speedup vs baseline: 8.8250x; 8.8250x over previous
//
#include <hip/hip_runtime.h>
#include <cstddef>

#define NSAMP 16
#define HW 409600
#define CPRED 6
#define EPS 1e-6

#define NB1 2048      // top-11 bits
#define NB2 2048      // next-11 bits
#define NB3 1024      // low-10 bits
#define L1SHIFT 21
#define BPSH 50       // blocks/sample, histogram passes (50*256*32 = 409600)
#define BPSD 100      // blocks/sample, dice pass
#define BPSC 25       // blocks/sample, compact refine passes

__device__ __forceinline__ unsigned sortkey(float f) {
    unsigned b = __float_as_uint(f);
    return (b & 0x80000000u) ? ~b : (b | 0x80000000u);   // larger float -> larger key
}
__device__ __forceinline__ float inv_sortkey(unsigned k) {
    unsigned b = (k & 0x80000000u) ? (k ^ 0x80000000u) : ~k;
    return __uint_as_float(b);
}
__device__ __forceinline__ float sigmoidf(float x) {
    return 1.0f / (1.0f + __expf(-x));
}

// Pass 1: pos/neg counts + level-1 LDS histogram + LDS-staged key compaction.
// No global atomics in the loop; one atomicAdd per block at the end.
__global__ void k_stats(const float* __restrict__ preds,
                        const float* __restrict__ targets,
                        const float* __restrict__ eff,
                        unsigned* __restrict__ hist,
                        unsigned* __restrict__ pos,
                        unsigned* __restrict__ negc,
                        unsigned* __restrict__ nkeys,   // may be null
                        unsigned* __restrict__ keys) {  // may be null
    const int n = blockIdx.y;
    const float4* p4 = (const float4*)(preds + (size_t)n * CPRED * HW);
    const float4* t4 = (const float4*)(targets + (size_t)n * 2 * HW);
    const float4* e4 = (const float4*)(eff + (size_t)n * HW);
    __shared__ unsigned h[4][NB1];     // 32 KB
    __shared__ unsigned kbuf[4][2048]; // 32 KB (each wave owns exactly 2048 elems)
    __shared__ unsigned kcnt[4];
    __shared__ unsigned kbase;
    for (int i = threadIdx.x; i < 4 * NB1; i += 256) ((unsigned*)h)[i] = 0;
    __syncthreads();
    const int wave = threadIdx.x >> 6;
    const int lane = threadIdx.x & 63;
    const unsigned long long lmask = (1ull << lane) - 1ull;
    unsigned lp = 0, run = 0;
    const int base = blockIdx.x * 2048;   // float4 units; 8192 floats/block
#pragma unroll
    for (int k = 0; k < 8; k++) {
        int i = base + k * 256 + threadIdx.x;
        float4 p = p4[i], t = t4[i], e = e4[i];
        float pa[4] = {p.x, p.y, p.z, p.w};
        float ta[4] = {t.x, t.y, t.z, t.w};
        float ea[4] = {e.x, e.y, e.z, e.w};
#pragma unroll
        for (int j = 0; j < 4; j++) {
            lp += (ta[j] > 0.5f && ea[j] > 0.5f) ? 1u : 0u;
            const bool isneg = (ta[j] <= 0.5f);
            unsigned long long bm = __ballot(isneg);
            if (isneg) {
                unsigned key = sortkey(pa[j]);
                atomicAdd(&h[wave][key >> L1SHIFT], 1u);
                int rank = __popcll(bm & lmask);
                kbuf[wave][run + rank] = key;
            }
            run += (unsigned)__popcll(bm);
        }
    }
    for (int off = 32; off; off >>= 1) lp += __shfl_down(lp, off, 64);
    if (lane == 0) {
        atomicAdd(&pos[n], lp);
        atomicAdd(&negc[n], run);
        kcnt[wave] = run;
    }
    __syncthreads();
    // flush hist (sparse)
    unsigned* gh = hist + (size_t)n * NB1;
    for (int b = threadIdx.x; b < NB1; b += 256) {
        unsigned s = h[0][b] + h[1][b] + h[2][b] + h[3][b];
        if (s) atomicAdd(&gh[b], s);
    }
    if (keys) {
        if (threadIdx.x == 0)
            kbase = atomicAdd(&nkeys[n], kcnt[0] + kcnt[1] + kcnt[2] + kcnt[3]);
        __syncthreads();
        unsigned off = kbase;
        for (int w = 0; w < wave; w++) off += kcnt[w];
        unsigned* kout = keys + (size_t)n * HW;
        const unsigned cnt = kcnt[wave];
        for (unsigned i = lane; i < cnt; i += 64) kout[off + i] = kbuf[wave][i];
    }
}

__global__ void k_scan1(unsigned* __restrict__ hist,
                        const unsigned* __restrict__ pos,
                        const unsigned* __restrict__ negc,
                        unsigned* __restrict__ b1,
                        unsigned* __restrict__ rem1,
                        unsigned* __restrict__ fb) {
    const int n = blockIdx.x;
    unsigned* gh = hist + (size_t)n * NB1;
    __shared__ unsigned bins[NB1];
    __shared__ unsigned chunkSum[256];
    for (int i = threadIdx.x; i < NB1; i += 256) bins[i] = gh[i];
    __syncthreads();
    for (int i = threadIdx.x; i < NB1; i += 256) gh[i] = 0;   // reuse for level 2
    unsigned s = 0;
#pragma unroll
    for (int j = 0; j < 8; j++) s += bins[threadIdx.x * 8 + j];
    chunkSum[threadIdx.x] = s;
    __syncthreads();
    if (threadIdx.x == 0) {
        const unsigned p = pos[n], nc = negc[n];
        const unsigned nn = min(p * 3u, nc);
        if (p == 0 || nn == 0) {
            b1[n] = 0xFFFFFFFFu; rem1[n] = 0; fb[n] = 1u;
        } else {
            fb[n] = 0u;
            unsigned cum = 0;
            int c;
            for (c = 255;; c--) {
                if (cum + chunkSum[c] >= nn) break;
                cum += chunkSum[c];
            }
            int b;
            for (b = c * 8 + 7;; b--) {
                unsigned hv = bins[b];
                if (cum + hv >= nn) break;
                cum += hv;
            }
            b1[n] = (unsigned)b;
            rem1[n] = nn - cum;
        }
    }
}

// Compact-path level-2: histogram next-11 bits of stored keys matching b1.
__global__ void k_refine2_c(const unsigned* __restrict__ keys,
                            const unsigned* __restrict__ nkeys,
                            const unsigned* __restrict__ b1,
                            unsigned* __restrict__ hist) {
    const int n = blockIdx.y;
    const unsigned B1 = b1[n];
    if (B1 == 0xFFFFFFFFu) return;
    const unsigned nk = nkeys[n];
    const unsigned* kin = keys + (size_t)n * HW;
    __shared__ unsigned h[4][NB2];
    for (int i = threadIdx.x; i < 4 * NB2; i += 256) ((unsigned*)h)[i] = 0;
    __syncthreads();
    const int wave = threadIdx.x >> 6;
    for (unsigned i = blockIdx.x * 256 + threadIdx.x; i < nk; i += BPSC * 256) {
        unsigned key = kin[i];
        if ((key >> L1SHIFT) == B1)
            atomicAdd(&h[wave][(key >> 10) & 0x7FFu], 1u);
    }
    __syncthreads();
    unsigned* gh = hist + (size_t)n * NB1;
    for (int b = threadIdx.x; b < NB2; b += 256) {
        unsigned s = h[0][b] + h[1][b] + h[2][b] + h[3][b];
        if (s) atomicAdd(&gh[b], s);
    }
}

// Fallback level-2 (re-reads pred/target) when ws too small for keys.
__global__ void k_refine2_g(const float* __restrict__ preds,
                            const float* __restrict__ targets,
                            const unsigned* __restrict__ b1,
                            unsigned* __restrict__ hist) {
    const int n = blockIdx.y;
    const unsigned B1 = b1[n];
    if (B1 == 0xFFFFFFFFu) return;
    const float4* p4 = (const float4*)(preds + (size_t)n * CPRED * HW);
    const float4* t4 = (const float4*)(targets + (size_t)n * 2 * HW);
    __shared__ unsigned h[4][NB2];
    for (int i = threadIdx.x; i < 4 * NB2; i += 256) ((unsigned*)h)[i] = 0;
    __syncthreads();
    const int wave = threadIdx.x >> 6;
    const int base = blockIdx.x * 2048;
#pragma unroll
    for (int k = 0; k < 8; k++) {
        int i = base + k * 256 + threadIdx.x;
        float4 p = p4[i], t = t4[i];
        float pa[4] = {p.x, p.y, p.z, p.w};
        float ta[4] = {t.x, t.y, t.z, t.w};
#pragma unroll
        for (int j = 0; j < 4; j++) {
            if (ta[j] <= 0.5f) {
                unsigned key = sortkey(pa[j]);
                if ((key >> L1SHIFT) == B1)
                    atomicAdd(&h[wave][(key >> 10) & 0x7FFu], 1u);
            }
        }
    }
    __syncthreads();
    unsigned* gh = hist + (size_t)n * NB1;
    for (int b = threadIdx.x; b < NB2; b += 256) {
        unsigned s = h[0][b] + h[1][b] + h[2][b] + h[3][b];
        if (s) atomicAdd(&gh[b], s);
    }
}

__global__ void k_scan2(unsigned* __restrict__ hist,
                        const unsigned* __restrict__ fb,
                        const unsigned* __restrict__ rem1,
                        unsigned* __restrict__ b2,
                        unsigned* __restrict__ rem2) {
    const int n = blockIdx.x;
    unsigned* gh = hist + (size_t)n * NB1;
    __shared__ unsigned bins[NB2];
    __shared__ unsigned chunkSum[256];
    for (int i = threadIdx.x; i < NB2; i += 256) bins[i] = gh[i];
    __syncthreads();
    for (int i = threadIdx.x; i < NB2; i += 256) gh[i] = 0;   // reuse for level 3
    unsigned s = 0;
#pragma unroll
    for (int j = 0; j < 8; j++) s += bins[threadIdx.x * 8 + j];
    chunkSum[threadIdx.x] = s;
    __syncthreads();
    if (threadIdx.x == 0) {
        if (fb[n]) { b2[n] = 0; rem2[n] = 0; return; }
        const unsigned r = rem1[n];
        unsigned cum = 0;
        int c;
        for (c = 255;; c--) {
            if (cum + chunkSum[c] >= r) break;
            cum += chunkSum[c];
        }
        int b;
        for (b = c * 8 + 7;; b--) {
            unsigned hv = bins[b];
            if (cum + hv >= r) break;
            cum += hv;
        }
        b2[n] = (unsigned)b;
        rem2[n] = r - cum;
    }
}

// Compact-path level-3.
__global__ void k_refine3_c(const unsigned* __restrict__ keys,
                            const unsigned* __restrict__ nkeys,
                            const unsigned* __restrict__ b1,
                            const unsigned* __restrict__ b2,
                            unsigned* __restrict__ hist) {
    const int n = blockIdx.y;
    const unsigned B1 = b1[n];
    if (B1 == 0xFFFFFFFFu) return;
    const unsigned prefix = (B1 << 11) | b2[n];
    const unsigned nk = nkeys[n];
    const unsigned* kin = keys + (size_t)n * HW;
    __shared__ unsigned h[4][NB3];
    for (int i = threadIdx.x; i < 4 * NB3; i += 256) ((unsigned*)h)[i] = 0;
    __syncthreads();
    const int wave = threadIdx.x >> 6;
    for (unsigned i = blockIdx.x * 256 + threadIdx.x; i < nk; i += BPSC * 256) {
        unsigned key = kin[i];
        if ((key >> 10) == prefix)
            atomicAdd(&h[wave][key & 0x3FFu], 1u);
    }
    __syncthreads();
    unsigned* gh = hist + (size_t)n * NB1;
    for (int b = threadIdx.x; b < NB3; b += 256) {
        unsigned s = h[0][b] + h[1][b] + h[2][b] + h[3][b];
        if (s) atomicAdd(&gh[b], s);
    }
}

// Fallback level-3.
__global__ void k_refine3_g(const float* __restrict__ preds,
                            const float* __restrict__ targets,
                            const unsigned* __restrict__ b1,
                            const unsigned* __restrict__ b2,
                            unsigned* __restrict__ hist) {
    const int n = blockIdx.y;
    const unsigned B1 = b1[n];
    if (B1 == 0xFFFFFFFFu) return;
    const unsigned prefix = (B1 << 11) | b2[n];
    const float4* p4 = (const float4*)(preds + (size_t)n * CPRED * HW);
    const float4* t4 = (const float4*)(targets + (size_t)n * 2 * HW);
    __shared__ unsigned h[4][NB3];
    for (int i = threadIdx.x; i < 4 * NB3; i += 256) ((unsigned*)h)[i] = 0;
    __syncthreads();
    const int wave = threadIdx.x >> 6;
    const int base = blockIdx.x * 2048;
#pragma unroll
    for (int k = 0; k < 8; k++) {
        int i = base + k * 256 + threadIdx.x;
        float4 p = p4[i], t = t4[i];
        float pa[4] = {p.x, p.y, p.z, p.w};
        float ta[4] = {t.x, t.y, t.z, t.w};
#pragma unroll
        for (int j = 0; j < 4; j++) {
            if (ta[j] <= 0.5f) {
                unsigned key = sortkey(pa[j]);
                if ((key >> 10) == prefix)
                    atomicAdd(&h[wave][key & 0x3FFu], 1u);
            }
        }
    }
    __syncthreads();
    unsigned* gh = hist + (size_t)n * NB1;
    for (int b = threadIdx.x; b < NB3; b += 256) {
        unsigned s = h[0][b] + h[1][b] + h[2][b] + h[3][b];
        if (s) atomicAdd(&gh[b], s);
    }
}

__global__ void k_scan3(const unsigned* __restrict__ hist,
                        const unsigned* __restrict__ fb,
                        const unsigned* __restrict__ b1,
                        const unsigned* __restrict__ b2,
                        const unsigned* __restrict__ rem2,
                        float* __restrict__ thr) {
    const int n = blockIdx.x;
    const unsigned* gh = hist + (size_t)n * NB1;
    __shared__ unsigned bins[NB3];
    __shared__ unsigned chunkSum[256];
    for (int i = threadIdx.x; i < NB3; i += 256) bins[i] = gh[i];
    __syncthreads();
    unsigned s = 0;
#pragma unroll
    for (int j = 0; j < 4; j++) s += bins[threadIdx.x * 4 + j];
    chunkSum[threadIdx.x] = s;
    __syncthreads();
    if (threadIdx.x == 0) {
        if (fb[n]) { thr[n] = -INFINITY; return; }
        const unsigned r = rem2[n];
        unsigned cum = 0;
        int c;
        for (c = 255;; c--) {
            if (cum + chunkSum[c] >= r) break;
            cum += chunkSum[c];
        }
        int b;
        for (b = c * 4 + 3;; b--) {
            unsigned hv = bins[b];
            if (cum + hv >= r) break;
            cum += hv;
        }
        thr[n] = inv_sortkey((b1[n] << L1SHIFT) | (b2[n] << 10) | (unsigned)b);
    }
}

// Pass 5: fused sigmoid + masks + 6 dice partial sums per block (no atomics).
__global__ void k_dice(const float* __restrict__ preds,
                       const float* __restrict__ targets,
                       const float* __restrict__ eff,
                       const float* __restrict__ thr,
                       const unsigned* __restrict__ fb,
                       double* __restrict__ partials) {
    const int n = blockIdx.y;
    const float4* p0 = (const float4*)(preds + (size_t)n * CPRED * HW);
    const float4* p1 = (const float4*)(preds + (size_t)n * CPRED * HW + HW);
    const float4* t0 = (const float4*)(targets + (size_t)n * 2 * HW);
    const float4* t1 = (const float4*)(targets + (size_t)n * 2 * HW + HW);
    const float4* e4 = (const float4*)(eff + (size_t)n * HW);
    const float th = thr[n];
    const bool fallback = fb[n] != 0;
    float sPG = 0.f, sP2 = 0.f, sG2 = 0.f, sPGk = 0.f, sP2k = 0.f, sG2k = 0.f;
    const int base = blockIdx.x * 1024;
#pragma unroll
    for (int k = 0; k < 4; k++) {
        int i = base + k * 256 + threadIdx.x;
        float4 a = p0[i], b = p1[i], t = t0[i], u = t1[i], e = e4[i];
        float pa[4] = {a.x, a.y, a.z, a.w};
        float pb[4] = {b.x, b.y, b.z, b.w};
        float ta[4] = {t.x, t.y, t.z, t.w};
        float ua[4] = {u.x, u.y, u.z, u.w};
        float ea[4] = {e.x, e.y, e.z, e.w};
#pragma unroll
        for (int j = 0; j < 4; j++) {
            float pt = sigmoidf(pa[j]);
            float pk = sigmoidf(pb[j]);
            float tbt = (ta[j] > 0.5f) ? 1.f : 0.f;
            float tbk = (ua[j] > 0.5f) ? 1.f : 0.f;
            float m;
            if (fallback) m = ea[j];
            else m = (((pa[j] >= th) || (ta[j] > 0.5f)) && (ea[j] > 0.5f)) ? 1.f : 0.f;
            float Pm = pt * m, Tm = tbt * m;
            sPG += Pm * Tm; sP2 += Pm * Pm; sG2 += Tm * Tm;
            float mk = (pt > 0.5f && ea[j] > 0.5f) ? 1.f : 0.f;
            float Pk = pk * mk, Tk = tbk * mk;
            sPGk += Pk * Tk; sP2k += Pk * Pk; sG2k += Tk * Tk;
        }
    }
    for (int off = 32; off; off >>= 1) {
        sPG  += __shfl_down(sPG, off, 64);
        sP2  += __shfl_down(sP2, off, 64);
        sG2  += __shfl_down(sG2, off, 64);
        sPGk += __shfl_down(sPGk, off, 64);
        sP2k += __shfl_down(sP2k, off, 64);
        sG2k += __shfl_down(sG2k, off, 64);
    }
    __shared__ double ws[4][6];
    if ((threadIdx.x & 63) == 0) {
        const int w = threadIdx.x >> 6;
        ws[w][0] = sPG;  ws[w][1] = sP2;  ws[w][2] = sG2;
        ws[w][3] = sPGk; ws[w][4] = sP2k; ws[w][5] = sG2k;
    }
    __syncthreads();
    if (threadIdx.x < 6) {
        double v = ws[0][threadIdx.x] + ws[1][threadIdx.x] +
                   ws[2][threadIdx.x] + ws[3][threadIdx.x];
        partials[((size_t)n * BPSD + blockIdx.x) * 6 + threadIdx.x] = v;
    }
}

// Pass 6: reduce partials, emit 32 outputs.
__global__ void k_final(const double* __restrict__ partials, float* __restrict__ out) {
    __shared__ double ssum[96];
    const int t = threadIdx.x;
    if (t < 96) {
        const int n = t / 6, c = t % 6;
        double a = 0.0;
        for (int b = 0; b < BPSD; b++) a += partials[((size_t)n * BPSD + b) * 6 + c];
        ssum[t] = a;
    }
    __syncthreads();
    if (t < NSAMP) {
        const double* s = &ssum[t * 6];
        out[t]         = (float)(1.0 - 2.0 * s[0] / (s[1] + s[2] + EPS));
        out[NSAMP + t] = (float)(1.0 - 2.0 * s[3] / (s[4] + s[5] + EPS));
    }
}

extern "C" void kernel_launch(void* const* d_in, const int* in_sizes, int n_in,
                              void* d_out, int out_size, void* d_ws, size_t ws_size,
                              hipStream_t stream) {
    const float* preds = (const float*)d_in[0];
    const float* targets = (const float*)d_in[1];
    const float* eff = (const float*)d_in[2];
    float* out = (float*)d_out;

    char* ws = (char*)d_ws;
    const size_t HIST_BYTES = (size_t)NSAMP * NB1 * sizeof(unsigned);   // 128 KiB
    unsigned* hist = (unsigned*)ws;
    unsigned* pos  = (unsigned*)(ws + HIST_BYTES);
    unsigned* negc = pos + NSAMP;
    unsigned* b1   = negc + NSAMP;
    unsigned* b2   = b1 + NSAMP;
    unsigned* rem1 = b2 + NSAMP;
    unsigned* rem2 = rem1 + NSAMP;
    unsigned* fb   = rem2 + NSAMP;
    float*    thr  = (float*)(fb + NSAMP);
    unsigned* nkeys = (unsigned*)(ws + HIST_BYTES + 512);               // 64 B
    double*   partials = (double*)(ws + HIST_BYTES + 1024);             // 16*100*6*8 = 76800 B
    const size_t KEYS_OFF = HIST_BYTES + 1024 + 80000;                  // 8-aligned
    unsigned* keys = (unsigned*)(ws + KEYS_OFF);
    const size_t KEYS_BYTES = (size_t)NSAMP * HW * sizeof(unsigned);    // 26.2 MB
    const bool compact = (ws_size >= KEYS_OFF + KEYS_BYTES);

    // zero hist + small arrays + nkeys (partials fully overwritten; keys count-guarded)
    hipMemsetAsync(d_ws, 0, HIST_BYTES + 1024, stream);

    dim3 bh(BPSH, NSAMP);
    dim3 bc(BPSC, NSAMP);
    dim3 bd(BPSD, NSAMP);
    k_stats<<<bh, 256, 0, stream>>>(preds, targets, eff, hist, pos, negc,
                                    compact ? nkeys : nullptr,
                                    compact ? keys : nullptr);
    k_scan1<<<NSAMP, 256, 0, stream>>>(hist, pos, negc, b1, rem1, fb);
    if (compact) k_refine2_c<<<bc, 256, 0, stream>>>(keys, nkeys, b1, hist);
    else         k_refine2_g<<<bh, 256, 0, stream>>>(preds, targets, b1, hist);
    k_scan2<<<NSAMP, 256, 0, stream>>>(hist, fb, rem1, b2, rem2);
    if (compact) k_refine3_c<<<bc, 256, 0, stream>>>(keys, nkeys, b1, b2, hist);
    else         k_refine3_g<<<bh, 256, 0, stream>>>(preds, targets, b1, b2, hist);
    k_scan3<<<NSAMP, 256, 0, stream>>>(hist, fb, b1, b2, rem2, thr);
    k_dice <<<bd, 256, 0, stream>>>(preds, targets, eff, thr, fb, partials);
    k_final<<<1, 128, 0, stream>>>(partials, out);
}

// Round 6
// 141.073 us; speedup vs baseline: 8.9304x; 1.0119x over previous
//
#include <hip/hip_runtime.h>
#include <cstddef>

#define NSAMP 16
#define HW 409600
#define CPRED 6
#define EPS 1e-6

#define NB1 2048      // top-11 bits
#define NB2 2048      // next-11 bits
#define NB3 1024      // low-10 bits
#define L1SHIFT 21
#define BPSH 50       // blocks/sample, histogram passes (50*256*32 = 409600)
#define BPSD 100      // blocks/sample, dice pass
#define BPSC 25       // blocks/sample, compact refine passes

__device__ __forceinline__ unsigned sortkey(float f) {
    unsigned b = __float_as_uint(f);
    return (b & 0x80000000u) ? ~b : (b | 0x80000000u);   // larger float -> larger key
}
__device__ __forceinline__ float inv_sortkey(unsigned k) {
    unsigned b = (k & 0x80000000u) ? (k ^ 0x80000000u) : ~k;
    return __uint_as_float(b);
}
__device__ __forceinline__ float sigmoidf(float x) {
    return 1.0f / (1.0f + __expf(-x));
}

// Zero the hist + small-array region (replaces pathologically slow runtime memset).
__global__ void k_zero(uint4* __restrict__ p, unsigned n4) {
    unsigned i = blockIdx.x * 256 + threadIdx.x;
    if (i < n4) p[i] = uint4{0, 0, 0, 0};
}

// Pass 1: pos/neg counts + level-1 LDS histogram + LDS-staged key compaction.
// No global atomics in the loop; one atomicAdd per block at the end.
__global__ void k_stats(const float* __restrict__ preds,
                        const float* __restrict__ targets,
                        const float* __restrict__ eff,
                        unsigned* __restrict__ hist,
                        unsigned* __restrict__ pos,
                        unsigned* __restrict__ negc,
                        unsigned* __restrict__ nkeys,   // may be null
                        unsigned* __restrict__ keys) {  // may be null
    const int n = blockIdx.y;
    const float4* p4 = (const float4*)(preds + (size_t)n * CPRED * HW);
    const float4* t4 = (const float4*)(targets + (size_t)n * 2 * HW);
    const float4* e4 = (const float4*)(eff + (size_t)n * HW);
    __shared__ unsigned h[4][NB1];     // 32 KB
    __shared__ unsigned kbuf[4][2048]; // 32 KB (each wave owns exactly 2048 elems)
    __shared__ unsigned kcnt[4];
    __shared__ unsigned kbase;
    for (int i = threadIdx.x; i < 4 * NB1; i += 256) ((unsigned*)h)[i] = 0;
    __syncthreads();
    const int wave = threadIdx.x >> 6;
    const int lane = threadIdx.x & 63;
    const unsigned long long lmask = (1ull << lane) - 1ull;
    unsigned lp = 0, run = 0;
    const int base = blockIdx.x * 2048;   // float4 units; 8192 floats/block
#pragma unroll
    for (int k = 0; k < 8; k++) {
        int i = base + k * 256 + threadIdx.x;
        float4 p = p4[i], t = t4[i], e = e4[i];
        float pa[4] = {p.x, p.y, p.z, p.w};
        float ta[4] = {t.x, t.y, t.z, t.w};
        float ea[4] = {e.x, e.y, e.z, e.w};
#pragma unroll
        for (int j = 0; j < 4; j++) {
            lp += (ta[j] > 0.5f && ea[j] > 0.5f) ? 1u : 0u;
            const bool isneg = (ta[j] <= 0.5f);
            unsigned long long bm = __ballot(isneg);
            if (isneg) {
                unsigned key = sortkey(pa[j]);
                atomicAdd(&h[wave][key >> L1SHIFT], 1u);
                int rank = __popcll(bm & lmask);
                kbuf[wave][run + rank] = key;
            }
            run += (unsigned)__popcll(bm);
        }
    }
    for (int off = 32; off; off >>= 1) lp += __shfl_down(lp, off, 64);
    if (lane == 0) {
        atomicAdd(&pos[n], lp);
        atomicAdd(&negc[n], run);
        kcnt[wave] = run;
    }
    __syncthreads();
    // flush hist (sparse)
    unsigned* gh = hist + (size_t)n * NB1;
    for (int b = threadIdx.x; b < NB1; b += 256) {
        unsigned s = h[0][b] + h[1][b] + h[2][b] + h[3][b];
        if (s) atomicAdd(&gh[b], s);
    }
    if (keys) {
        if (threadIdx.x == 0)
            kbase = atomicAdd(&nkeys[n], kcnt[0] + kcnt[1] + kcnt[2] + kcnt[3]);
        __syncthreads();
        unsigned off = kbase;
        for (int w = 0; w < wave; w++) off += kcnt[w];
        unsigned* kout = keys + (size_t)n * HW;
        const unsigned cnt = kcnt[wave];
        for (unsigned i = lane; i < cnt; i += 64) kout[off + i] = kbuf[wave][i];
    }
}

__global__ void k_scan1(unsigned* __restrict__ hist,
                        const unsigned* __restrict__ pos,
                        const unsigned* __restrict__ negc,
                        unsigned* __restrict__ b1,
                        unsigned* __restrict__ rem1,
                        unsigned* __restrict__ fb) {
    const int n = blockIdx.x;
    unsigned* gh = hist + (size_t)n * NB1;
    __shared__ unsigned bins[NB1];
    __shared__ unsigned chunkSum[256];
    for (int i = threadIdx.x; i < NB1; i += 256) bins[i] = gh[i];
    __syncthreads();
    for (int i = threadIdx.x; i < NB1; i += 256) gh[i] = 0;   // reuse for level 2
    unsigned s = 0;
#pragma unroll
    for (int j = 0; j < 8; j++) s += bins[threadIdx.x * 8 + j];
    chunkSum[threadIdx.x] = s;
    __syncthreads();
    if (threadIdx.x == 0) {
        const unsigned p = pos[n], nc = negc[n];
        const unsigned nn = min(p * 3u, nc);
        if (p == 0 || nn == 0) {
            b1[n] = 0xFFFFFFFFu; rem1[n] = 0; fb[n] = 1u;
        } else {
            fb[n] = 0u;
            unsigned cum = 0;
            int c;
            for (c = 255;; c--) {
                if (cum + chunkSum[c] >= nn) break;
                cum += chunkSum[c];
            }
            int b;
            for (b = c * 8 + 7;; b--) {
                unsigned hv = bins[b];
                if (cum + hv >= nn) break;
                cum += hv;
            }
            b1[n] = (unsigned)b;
            rem1[n] = nn - cum;
        }
    }
}

// Compact-path level-2: histogram next-11 bits of stored keys matching b1.
__global__ void k_refine2_c(const unsigned* __restrict__ keys,
                            const unsigned* __restrict__ nkeys,
                            const unsigned* __restrict__ b1,
                            unsigned* __restrict__ hist) {
    const int n = blockIdx.y;
    const unsigned B1 = b1[n];
    if (B1 == 0xFFFFFFFFu) return;
    const unsigned nk = nkeys[n];
    const unsigned* kin = keys + (size_t)n * HW;
    __shared__ unsigned h[4][NB2];
    for (int i = threadIdx.x; i < 4 * NB2; i += 256) ((unsigned*)h)[i] = 0;
    __syncthreads();
    const int wave = threadIdx.x >> 6;
    for (unsigned i = blockIdx.x * 256 + threadIdx.x; i < nk; i += BPSC * 256) {
        unsigned key = kin[i];
        if ((key >> L1SHIFT) == B1)
            atomicAdd(&h[wave][(key >> 10) & 0x7FFu], 1u);
    }
    __syncthreads();
    unsigned* gh = hist + (size_t)n * NB1;
    for (int b = threadIdx.x; b < NB2; b += 256) {
        unsigned s = h[0][b] + h[1][b] + h[2][b] + h[3][b];
        if (s) atomicAdd(&gh[b], s);
    }
}

// Fallback level-2 (re-reads pred/target) when ws too small for keys.
__global__ void k_refine2_g(const float* __restrict__ preds,
                            const float* __restrict__ targets,
                            const unsigned* __restrict__ b1,
                            unsigned* __restrict__ hist) {
    const int n = blockIdx.y;
    const unsigned B1 = b1[n];
    if (B1 == 0xFFFFFFFFu) return;
    const float4* p4 = (const float4*)(preds + (size_t)n * CPRED * HW);
    const float4* t4 = (const float4*)(targets + (size_t)n * 2 * HW);
    __shared__ unsigned h[4][NB2];
    for (int i = threadIdx.x; i < 4 * NB2; i += 256) ((unsigned*)h)[i] = 0;
    __syncthreads();
    const int wave = threadIdx.x >> 6;
    const int base = blockIdx.x * 2048;
#pragma unroll
    for (int k = 0; k < 8; k++) {
        int i = base + k * 256 + threadIdx.x;
        float4 p = p4[i], t = t4[i];
        float pa[4] = {p.x, p.y, p.z, p.w};
        float ta[4] = {t.x, t.y, t.z, t.w};
#pragma unroll
        for (int j = 0; j < 4; j++) {
            if (ta[j] <= 0.5f) {
                unsigned key = sortkey(pa[j]);
                if ((key >> L1SHIFT) == B1)
                    atomicAdd(&h[wave][(key >> 10) & 0x7FFu], 1u);
            }
        }
    }
    __syncthreads();
    unsigned* gh = hist + (size_t)n * NB1;
    for (int b = threadIdx.x; b < NB2; b += 256) {
        unsigned s = h[0][b] + h[1][b] + h[2][b] + h[3][b];
        if (s) atomicAdd(&gh[b], s);
    }
}

__global__ void k_scan2(unsigned* __restrict__ hist,
                        const unsigned* __restrict__ fb,
                        const unsigned* __restrict__ rem1,
                        unsigned* __restrict__ b2,
                        unsigned* __restrict__ rem2) {
    const int n = blockIdx.x;
    unsigned* gh = hist + (size_t)n * NB1;
    __shared__ unsigned bins[NB2];
    __shared__ unsigned chunkSum[256];
    for (int i = threadIdx.x; i < NB2; i += 256) bins[i] = gh[i];
    __syncthreads();
    for (int i = threadIdx.x; i < NB2; i += 256) gh[i] = 0;   // reuse for level 3
    unsigned s = 0;
#pragma unroll
    for (int j = 0; j < 8; j++) s += bins[threadIdx.x * 8 + j];
    chunkSum[threadIdx.x] = s;
    __syncthreads();
    if (threadIdx.x == 0) {
        if (fb[n]) { b2[n] = 0; rem2[n] = 0; return; }
        const unsigned r = rem1[n];
        unsigned cum = 0;
        int c;
        for (c = 255;; c--) {
            if (cum + chunkSum[c] >= r) break;
            cum += chunkSum[c];
        }
        int b;
        for (b = c * 8 + 7;; b--) {
            unsigned hv = bins[b];
            if (cum + hv >= r) break;
            cum += hv;
        }
        b2[n] = (unsigned)b;
        rem2[n] = r - cum;
    }
}

// Compact-path level-3.
__global__ void k_refine3_c(const unsigned* __restrict__ keys,
                            const unsigned* __restrict__ nkeys,
                            const unsigned* __restrict__ b1,
                            const unsigned* __restrict__ b2,
                            unsigned* __restrict__ hist) {
    const int n = blockIdx.y;
    const unsigned B1 = b1[n];
    if (B1 == 0xFFFFFFFFu) return;
    const unsigned prefix = (B1 << 11) | b2[n];
    const unsigned nk = nkeys[n];
    const unsigned* kin = keys + (size_t)n * HW;
    __shared__ unsigned h[4][NB3];
    for (int i = threadIdx.x; i < 4 * NB3; i += 256) ((unsigned*)h)[i] = 0;
    __syncthreads();
    const int wave = threadIdx.x >> 6;
    for (unsigned i = blockIdx.x * 256 + threadIdx.x; i < nk; i += BPSC * 256) {
        unsigned key = kin[i];
        if ((key >> 10) == prefix)
            atomicAdd(&h[wave][key & 0x3FFu], 1u);
    }
    __syncthreads();
    unsigned* gh = hist + (size_t)n * NB1;
    for (int b = threadIdx.x; b < NB3; b += 256) {
        unsigned s = h[0][b] + h[1][b] + h[2][b] + h[3][b];
        if (s) atomicAdd(&gh[b], s);
    }
}

// Fallback level-3.
__global__ void k_refine3_g(const float* __restrict__ preds,
                            const float* __restrict__ targets,
                            const unsigned* __restrict__ b1,
                            const unsigned* __restrict__ b2,
                            unsigned* __restrict__ hist) {
    const int n = blockIdx.y;
    const unsigned B1 = b1[n];
    if (B1 == 0xFFFFFFFFu) return;
    const unsigned prefix = (B1 << 11) | b2[n];
    const float4* p4 = (const float4*)(preds + (size_t)n * CPRED * HW);
    const float4* t4 = (const float4*)(targets + (size_t)n * 2 * HW);
    __shared__ unsigned h[4][NB3];
    for (int i = threadIdx.x; i < 4 * NB3; i += 256) ((unsigned*)h)[i] = 0;
    __syncthreads();
    const int wave = threadIdx.x >> 6;
    const int base = blockIdx.x * 2048;
#pragma unroll
    for (int k = 0; k < 8; k++) {
        int i = base + k * 256 + threadIdx.x;
        float4 p = p4[i], t = t4[i];
        float pa[4] = {p.x, p.y, p.z, p.w};
        float ta[4] = {t.x, t.y, t.z, t.w};
#pragma unroll
        for (int j = 0; j < 4; j++) {
            if (ta[j] <= 0.5f) {
                unsigned key = sortkey(pa[j]);
                if ((key >> 10) == prefix)
                    atomicAdd(&h[wave][key & 0x3FFu], 1u);
            }
        }
    }
    __syncthreads();
    unsigned* gh = hist + (size_t)n * NB1;
    for (int b = threadIdx.x; b < NB3; b += 256) {
        unsigned s = h[0][b] + h[1][b] + h[2][b] + h[3][b];
        if (s) atomicAdd(&gh[b], s);
    }
}

__global__ void k_scan3(const unsigned* __restrict__ hist,
                        const unsigned* __restrict__ fb,
                        const unsigned* __restrict__ b1,
                        const unsigned* __restrict__ b2,
                        const unsigned* __restrict__ rem2,
                        float* __restrict__ thr) {
    const int n = blockIdx.x;
    const unsigned* gh = hist + (size_t)n * NB1;
    __shared__ unsigned bins[NB3];
    __shared__ unsigned chunkSum[256];
    for (int i = threadIdx.x; i < NB3; i += 256) bins[i] = gh[i];
    __syncthreads();
    unsigned s = 0;
#pragma unroll
    for (int j = 0; j < 4; j++) s += bins[threadIdx.x * 4 + j];
    chunkSum[threadIdx.x] = s;
    __syncthreads();
    if (threadIdx.x == 0) {
        if (fb[n]) { thr[n] = -INFINITY; return; }
        const unsigned r = rem2[n];
        unsigned cum = 0;
        int c;
        for (c = 255;; c--) {
            if (cum + chunkSum[c] >= r) break;
            cum += chunkSum[c];
        }
        int b;
        for (b = c * 4 + 3;; b--) {
            unsigned hv = bins[b];
            if (cum + hv >= r) break;
            cum += hv;
        }
        thr[n] = inv_sortkey((b1[n] << L1SHIFT) | (b2[n] << 10) | (unsigned)b);
    }
}

// Pass 5: fused sigmoid + masks + 6 dice partial sums per block (no atomics).
__global__ void k_dice(const float* __restrict__ preds,
                       const float* __restrict__ targets,
                       const float* __restrict__ eff,
                       const float* __restrict__ thr,
                       const unsigned* __restrict__ fb,
                       double* __restrict__ partials) {
    const int n = blockIdx.y;
    const float4* p0 = (const float4*)(preds + (size_t)n * CPRED * HW);
    const float4* p1 = (const float4*)(preds + (size_t)n * CPRED * HW + HW);
    const float4* t0 = (const float4*)(targets + (size_t)n * 2 * HW);
    const float4* t1 = (const float4*)(targets + (size_t)n * 2 * HW + HW);
    const float4* e4 = (const float4*)(eff + (size_t)n * HW);
    const float th = thr[n];
    const bool fallback = fb[n] != 0;
    float sPG = 0.f, sP2 = 0.f, sG2 = 0.f, sPGk = 0.f, sP2k = 0.f, sG2k = 0.f;
    const int base = blockIdx.x * 1024;
#pragma unroll
    for (int k = 0; k < 4; k++) {
        int i = base + k * 256 + threadIdx.x;
        float4 a = p0[i], b = p1[i], t = t0[i], u = t1[i], e = e4[i];
        float pa[4] = {a.x, a.y, a.z, a.w};
        float pb[4] = {b.x, b.y, b.z, b.w};
        float ta[4] = {t.x, t.y, t.z, t.w};
        float ua[4] = {u.x, u.y, u.z, u.w};
        float ea[4] = {e.x, e.y, e.z, e.w};
#pragma unroll
        for (int j = 0; j < 4; j++) {
            float pt = sigmoidf(pa[j]);
            float pk = sigmoidf(pb[j]);
            float tbt = (ta[j] > 0.5f) ? 1.f : 0.f;
            float tbk = (ua[j] > 0.5f) ? 1.f : 0.f;
            float m;
            if (fallback) m = ea[j];
            else m = (((pa[j] >= th) || (ta[j] > 0.5f)) && (ea[j] > 0.5f)) ? 1.f : 0.f;
            float Pm = pt * m, Tm = tbt * m;
            sPG += Pm * Tm; sP2 += Pm * Pm; sG2 += Tm * Tm;
            float mk = (pt > 0.5f && ea[j] > 0.5f) ? 1.f : 0.f;
            float Pk = pk * mk, Tk = tbk * mk;
            sPGk += Pk * Tk; sP2k += Pk * Pk; sG2k += Tk * Tk;
        }
    }
    for (int off = 32; off; off >>= 1) {
        sPG  += __shfl_down(sPG, off, 64);
        sP2  += __shfl_down(sP2, off, 64);
        sG2  += __shfl_down(sG2, off, 64);
        sPGk += __shfl_down(sPGk, off, 64);
        sP2k += __shfl_down(sP2k, off, 64);
        sG2k += __shfl_down(sG2k, off, 64);
    }
    __shared__ double ws[4][6];
    if ((threadIdx.x & 63) == 0) {
        const int w = threadIdx.x >> 6;
        ws[w][0] = sPG;  ws[w][1] = sP2;  ws[w][2] = sG2;
        ws[w][3] = sPGk; ws[w][4] = sP2k; ws[w][5] = sG2k;
    }
    __syncthreads();
    if (threadIdx.x < 6) {
        double v = ws[0][threadIdx.x] + ws[1][threadIdx.x] +
                   ws[2][threadIdx.x] + ws[3][threadIdx.x];
        partials[((size_t)n * BPSD + blockIdx.x) * 6 + threadIdx.x] = v;
    }
}

// Pass 6: reduce partials, emit 32 outputs.
__global__ void k_final(const double* __restrict__ partials, float* __restrict__ out) {
    __shared__ double ssum[96];
    const int t = threadIdx.x;
    if (t < 96) {
        const int n = t / 6, c = t % 6;
        double a = 0.0;
        for (int b = 0; b < BPSD; b++) a += partials[((size_t)n * BPSD + b) * 6 + c];
        ssum[t] = a;
    }
    __syncthreads();
    if (t < NSAMP) {
        const double* s = &ssum[t * 6];
        out[t]         = (float)(1.0 - 2.0 * s[0] / (s[1] + s[2] + EPS));
        out[NSAMP + t] = (float)(1.0 - 2.0 * s[3] / (s[4] + s[5] + EPS));
    }
}

extern "C" void kernel_launch(void* const* d_in, const int* in_sizes, int n_in,
                              void* d_out, int out_size, void* d_ws, size_t ws_size,
                              hipStream_t stream) {
    const float* preds = (const float*)d_in[0];
    const float* targets = (const float*)d_in[1];
    const float* eff = (const float*)d_in[2];
    float* out = (float*)d_out;

    char* ws = (char*)d_ws;
    const size_t HIST_BYTES = (size_t)NSAMP * NB1 * sizeof(unsigned);   // 128 KiB
    unsigned* hist = (unsigned*)ws;
    unsigned* pos  = (unsigned*)(ws + HIST_BYTES);
    unsigned* negc = pos + NSAMP;
    unsigned* b1   = negc + NSAMP;
    unsigned* b2   = b1 + NSAMP;
    unsigned* rem1 = b2 + NSAMP;
    unsigned* rem2 = rem1 + NSAMP;
    unsigned* fb   = rem2 + NSAMP;
    float*    thr  = (float*)(fb + NSAMP);
    unsigned* nkeys = (unsigned*)(ws + HIST_BYTES + 512);               // 64 B
    double*   partials = (double*)(ws + HIST_BYTES + 1024);             // 16*100*6*8 = 76800 B
    const size_t KEYS_OFF = HIST_BYTES + 1024 + 80000;                  // 8-aligned
    unsigned* keys = (unsigned*)(ws + KEYS_OFF);
    const size_t KEYS_BYTES = (size_t)NSAMP * HW * sizeof(unsigned);    // 26.2 MB
    const bool compact = (ws_size >= KEYS_OFF + KEYS_BYTES);

    // zero hist + small arrays + nkeys with a custom kernel:
    // hipMemsetAsync's fill kernel measured 88us for 132KB (1.6 GB/s) in-graph.
    const unsigned ZERO_N4 = (unsigned)((HIST_BYTES + 1024) / 16);      // 8256 uint4
    k_zero<<<(ZERO_N4 + 255) / 256, 256, 0, stream>>>((uint4*)ws, ZERO_N4);

    dim3 bh(BPSH, NSAMP);
    dim3 bc(BPSC, NSAMP);
    dim3 bd(BPSD, NSAMP);
    k_stats<<<bh, 256, 0, stream>>>(preds, targets, eff, hist, pos, negc,
                                    compact ? nkeys : nullptr,
                                    compact ? keys : nullptr);
    k_scan1<<<NSAMP, 256, 0, stream>>>(hist, pos, negc, b1, rem1, fb);
    if (compact) k_refine2_c<<<bc, 256, 0, stream>>>(keys, nkeys, b1, hist);
    else         k_refine2_g<<<bh, 256, 0, stream>>>(preds, targets, b1, hist);
    k_scan2<<<NSAMP, 256, 0, stream>>>(hist, fb, rem1, b2, rem2);
    if (compact) k_refine3_c<<<bc, 256, 0, stream>>>(keys, nkeys, b1, b2, hist);
    else         k_refine3_g<<<bh, 256, 0, stream>>>(preds, targets, b1, b2, hist);
    k_scan3<<<NSAMP, 256, 0, stream>>>(hist, fb, b1, b2, rem2, thr);
    k_dice <<<bd, 256, 0, stream>>>(preds, targets, eff, thr, fb, partials);
    k_final<<<1, 128, 0, stream>>>(partials, out);
}